// Round 17
// baseline (753.550 us; speedup 1.0000x reference)
//
#include <hip/hip_runtime.h>
#include <hip/hip_bf16.h>
#include <cstdint>
#include <cstddef>

#define NN 50000
#define NE 800000
#define ETOT (NN + NE)   // 850000 edges incl. self loops

typedef float f32x4 __attribute__((ext_vector_type(4)));
typedef short s16x8 __attribute__((ext_vector_type(8)));

__device__ __forceinline__ unsigned short f2bf(float f) {
  unsigned u = __float_as_uint(f);
  u += 0x7FFFu + ((u >> 16) & 1u);   // RNE
  return (unsigned short)(u >> 16);
}
__device__ __forceinline__ float bf2f(unsigned short u) {
  return __uint_as_float(((unsigned)u) << 16);
}
__device__ __forceinline__ unsigned cvtpk(float lo, float hi) {  // 2xf32 -> packed bf16 (RNE)
  unsigned r;
  asm("v_cvt_pk_bf16_f32 %0, %1, %2" : "=v"(r) : "v"(lo), "v"(hi));
  return r;
}
typedef const __attribute__((address_space(1))) void* gas_t;
typedef __attribute__((address_space(3))) void* las_t;
__device__ __forceinline__ void gload_lds16(const void* g, void* l) {
  __builtin_amdgcn_global_load_lds((gas_t)g, (las_t)l, 16, 0, 0);
}

// edge_index may arrive as int32 or int64; detect on device. Also zeros dhist.
__global__ void detect_i64(const void* __restrict__ ei, int* __restrict__ flag,
                           int* __restrict__ dhist) {
  const long long v = ((const long long*)ei)[threadIdx.x];
  const bool ok = (v >= 0 && v < NN);
  const unsigned long long m = __ballot(ok);
  if (threadIdx.x == 0) *flag = (m == ~0ULL) ? 1 : 0;
  #pragma unroll
  for (int j = 0; j < 4; ++j) dhist[threadIdx.x * 4 + j] = 0;
}
__device__ __forceinline__ void load_edge(const void* __restrict__ ei, int is64,
                                          int eidx, int& src, int& dst) {
  if (eidx >= NE) { src = dst = eidx - NE; return; }
  if (is64) {
    src = (int)((const long long*)ei)[eidx];
    dst = (int)((const long long*)ei)[NE + eidx];
  } else {
    src = ((const int*)ei)[eidx];
    dst = ((const int*)ei)[NE + eidx];
  }
}

// ---------------- CSR build (by dst) + degree-sort plumbing ----------------
__global__ __launch_bounds__(256) void csr_hist(
    const void* __restrict__ ei, const int* __restrict__ flag, int* __restrict__ cnt)
{
  const int e = blockIdx.x * 256 + threadIdx.x;
  if (e >= ETOT) return;
  int src, dst;
  load_edge(ei, *flag, e, src, dst);
  atomicAdd(&cnt[dst], 1);
}

// per-block inclusive scan of cnt -> rp1, block sums -> bsum; also degree histogram
__global__ __launch_bounds__(256) void scan_blk(
    const int* __restrict__ cnt, int* __restrict__ rp1, int* __restrict__ bsum,
    int* __restrict__ dhist)
{
  const int tid = threadIdx.x, lane = tid & 63, w = tid >> 6;
  const int i = blockIdx.x * 256 + tid;
  int v = (i < NN) ? cnt[i] : 0;
  if (i < NN) atomicAdd(&dhist[v < 255 ? v : 255], 1);
  int s = v;
  #pragma unroll
  for (int off = 1; off < 64; off <<= 1) {
    int t = __shfl_up(s, off);
    if (lane >= off) s += t;
  }
  __shared__ int wsum[4];
  if (lane == 63) wsum[w] = s;
  __syncthreads();
  int add = 0;
  #pragma unroll
  for (int k = 0; k < 4; ++k) if (k < w) add += wsum[k];
  s += add;
  if (i < NN) rp1[i] = s;
  if (tid == 255) bsum[blockIdx.x] = s;
}

// scan block sums (nb<=256) AND exclusive-scan 256 degree bins -> dcur
__global__ __launch_bounds__(256) void scan_tops(
    int* __restrict__ bsum, int nb, const int* __restrict__ dhist, int* __restrict__ dcur)
{
  const int tid = threadIdx.x, lane = tid & 63, w = tid >> 6;
  __shared__ int wsum[4];
  {
    int s = (tid < nb) ? bsum[tid] : 0;
    #pragma unroll
    for (int off = 1; off < 64; off <<= 1) {
      int t = __shfl_up(s, off);
      if (lane >= off) s += t;
    }
    if (lane == 63) wsum[w] = s;
    __syncthreads();
    int add = 0;
    #pragma unroll
    for (int k = 0; k < 4; ++k) if (k < w) add += wsum[k];
    s += add;
    if (tid < nb) bsum[tid] = s;   // inclusive block sums
  }
  __syncthreads();
  {
    const int v = dhist[tid];
    int s = v;
    #pragma unroll
    for (int off = 1; off < 64; off <<= 1) {
      int t = __shfl_up(s, off);
      if (lane >= off) s += t;
    }
    if (lane == 63) wsum[w] = s;
    __syncthreads();
    int add = 0;
    #pragma unroll
    for (int k = 0; k < 4; ++k) if (k < w) add += wsum[k];
    s += add;
    dcur[tid] = s - v;   // exclusive bin offsets (doubles as scatter cursor)
  }
}

// finalize rowptr AND scatter nodes into degree-sorted order[]
__global__ __launch_bounds__(256) void scan_add(
    const int* __restrict__ bsum, int* __restrict__ rowptr,
    const int* __restrict__ cnt, int* __restrict__ dcur, int* __restrict__ order)
{
  const int i = blockIdx.x * 256 + threadIdx.x;
  if (i == 0) rowptr[0] = 0;
  if (i < NN) {
    rowptr[i + 1] += (blockIdx.x > 0) ? bsum[blockIdx.x - 1] : 0;
    const int d = cnt[i] < 255 ? cnt[i] : 255;
    const int pos = atomicAdd(&dcur[d], 1);
    order[pos] = i;
  }
}

// cur[] preloaded with rowptr[] (d2d copy); pos = cur[dst]++ directly indexes colv
__global__ __launch_bounds__(256) void csr_scatter(
    const void* __restrict__ ei, const int* __restrict__ flag,
    int* __restrict__ cur, int* __restrict__ colv)
{
  const int e = blockIdx.x * 256 + threadIdx.x;
  if (e >= ETOT) return;
  int src, dst;
  load_edge(ei, *flag, e, src, dst);
  const int pos = atomicAdd(&cur[dst], 1);
  colv[pos] = src;
}

// ---------------- gemm8: 256x128 tile, 8 waves, BK=32, double-buffered ----------
template<bool AF32>
__global__ __launch_bounds__(512) void gemm8(
    const void* __restrict__ Av, const unsigned short* __restrict__ BT,
    void* __restrict__ Cv, const float* __restrict__ bias,
    int M, int K, int Ncols, int out_bf16, int nbx, int nwg)
{
  constexpr int ABYTES = AF32 ? 256 * 32 * 4 : 256 * 32 * 2;
  __shared__ __align__(16) unsigned char Araw[2][ABYTES];
  __shared__ __align__(16) unsigned short Bs[2][128 * 32];

  int bid = blockIdx.x;
  {  // bijective XCD-chunked swizzle (m204)
    const int q = nwg >> 3, r = nwg & 7;
    const int xcd = bid & 7, idx = bid >> 3;
    bid = (xcd < r ? xcd * (q + 1) : r * (q + 1) + (xcd - r) * q) + idx;
  }
  const int bx = bid % nbx, by = bid / nbx;
  const int row0 = by * 256, col0 = bx * 128;
  const int tid = threadIdx.x, wave = tid >> 6, lane = tid & 63;
  const int l16 = lane & 15, lq = lane >> 4;
  const int wr = wave >> 1, wc = wave & 1;

  const unsigned short* Abf = (const unsigned short*)Av;
  const float*          Af  = (const float*)Av;

  f32x4 acc[4][4];
  #pragma unroll
  for (int i = 0; i < 4; ++i)
    #pragma unroll
    for (int j = 0; j < 4; ++j)
      #pragma unroll
      for (int r = 0; r < 4; ++r) acc[i][j][r] = 0.f;

  auto stageA = [&](int buf, int k0) {
    if constexpr (AF32) {
      #pragma unroll
      for (int j = 0; j < 4; ++j) {
        const int c = tid + 512 * j;
        const int row = c >> 3;
        const int kg = (c & 7) ^ (row & 7);
        int gr = row0 + row; if (gr >= M) gr = M - 1;
        gload_lds16(Af + (size_t)gr * K + k0 + kg * 4, Araw[buf] + c * 16);
      }
    } else {
      #pragma unroll
      for (int j = 0; j < 2; ++j) {
        const int c = tid + 512 * j;
        const int row = c >> 2, part = c & 3;
        int gr = row0 + row; if (gr >= M) gr = M - 1;
        gload_lds16(Abf + (size_t)gr * K + k0 + part * 8, Araw[buf] + c * 16);
      }
    }
  };
  auto stageB = [&](int buf, int k0) {
    const int c = tid;
    const int row = c >> 2, part = c & 3;
    gload_lds16(BT + (size_t)(col0 + row) * K + k0 + part * 8,
                (unsigned char*)Bs[buf] + c * 16);
  };

  const int nt = K >> 5;
  stageA(0, 0);
  stageB(0, 0);
  __syncthreads();

  for (int t = 0; t < nt; ++t) {
    const int cur = t & 1, nxt = cur ^ 1;
    if (t + 1 < nt) {
      stageA(nxt, (t + 1) << 5);
      stageB(nxt, (t + 1) << 5);
    }

    s16x8 af[4], bf[4];
    if constexpr (AF32) {
      const float* Ab = (const float*)Araw[cur];
      #pragma unroll
      for (int f = 0; f < 4; ++f) {
        const int row = wr * 64 + f * 16 + l16;
        const int s0 = (row << 3) + ((2 * lq)     ^ (row & 7));
        const int s1 = (row << 3) + ((2 * lq + 1) ^ (row & 7));
        const float4 f0 = *(const float4*)(Ab + s0 * 4);
        const float4 f1 = *(const float4*)(Ab + s1 * 4);
        uint4 w;
        w.x = cvtpk(f0.x, f0.y); w.y = cvtpk(f0.z, f0.w);
        w.z = cvtpk(f1.x, f1.y); w.w = cvtpk(f1.z, f1.w);
        af[f] = *(s16x8*)&w;
      }
    } else {
      const unsigned short* Ab = (const unsigned short*)Araw[cur];
      #pragma unroll
      for (int f = 0; f < 4; ++f)
        af[f] = *(const s16x8*)&Ab[(wr * 64 + f * 16 + l16) * 32 + lq * 8];
    }
    #pragma unroll
    for (int f = 0; f < 4; ++f)
      bf[f] = *(const s16x8*)&Bs[cur][(wc * 64 + f * 16 + l16) * 32 + lq * 8];

    #pragma unroll
    for (int fm = 0; fm < 4; ++fm)
      #pragma unroll
      for (int fn = 0; fn < 4; ++fn)
        acc[fm][fn] = __builtin_amdgcn_mfma_f32_16x16x32_bf16(af[fm], bf[fn], acc[fm][fn], 0, 0, 0);

    __syncthreads();
  }

  float bv[4];
  #pragma unroll
  for (int fn = 0; fn < 4; ++fn)
    bv[fn] = bias ? bias[col0 + wc * 64 + fn * 16 + l16] : 0.f;

  // C/D layout: col = l16, row = lq*4 + r (verified m89/m91 + rounds 2-16)
  #pragma unroll
  for (int fm = 0; fm < 4; ++fm) {
    #pragma unroll
    for (int r = 0; r < 4; ++r) {
      const int row = row0 + wr * 64 + fm * 16 + lq * 4 + r;
      if (row < M) {
        #pragma unroll
        for (int fn = 0; fn < 4; ++fn) {
          const int col = col0 + wc * 64 + fn * 16 + l16;
          const float v = acc[fm][fn][r] + bv[fn];
          if (out_bf16) ((unsigned short*)Cv)[(size_t)row * Ncols + col] = f2bf(v);
          else          ((float*)Cv)[(size_t)row * Ncols + col] = v;
        }
      }
    }
  }
}

// ---------------- gemm_t: 128x128 tile, 4 waves — small GEMMs ----
// AMODE: 0 = A bf16; 2 = A fp32 + fused BN affine+ReLU at frag read.
// BNS: fused BN stats, register-first (R15-proven).
template<int AMODE, bool BNS>
__global__ __launch_bounds__(256) void gemm_t(
    const void* __restrict__ Av, const unsigned short* __restrict__ BT,
    void* __restrict__ Cv, const float* __restrict__ bias,
    const float* __restrict__ abn, float* __restrict__ bnsum,
    int M, int K, int Ncols, int out_bf16, int nbx, int nwg)
{
  constexpr bool AF32 = (AMODE > 0);
  __shared__ __align__(16) unsigned char Araw[2][AF32 ? 128 * 32 * 4 : 128 * 32 * 2];
  __shared__ __align__(16) unsigned short Bs[2][128 * 32];

  int bid = blockIdx.x;
  {
    const int q = nwg >> 3, r = nwg & 7;
    const int xcd = bid & 7, idx = bid >> 3;
    bid = (xcd < r ? xcd * (q + 1) : r * (q + 1) + (xcd - r) * q) + idx;
  }
  const int bx = bid % nbx, by = bid / nbx;
  const int row0 = by * 128, col0 = bx * 128;
  const int tid = threadIdx.x, wave = tid >> 6, lane = tid & 63;
  const int l16 = lane & 15, lq = lane >> 4;
  const int wr = wave >> 1, wc = wave & 1;

  const unsigned short* Abf = (const unsigned short*)Av;
  const float*          Af  = (const float*)Av;

  f32x4 acc[4][4];
  #pragma unroll
  for (int i = 0; i < 4; ++i)
    #pragma unroll
    for (int j = 0; j < 4; ++j)
      #pragma unroll
      for (int r = 0; r < 4; ++r) acc[i][j][r] = 0.f;

  auto stageA = [&](int buf, int k0) {
    if constexpr (AF32) {
      #pragma unroll
      for (int j = 0; j < 4; ++j) {
        const int c = tid + 256 * j;
        const int row = c >> 3;
        const int kg = (c & 7) ^ (row & 7);
        int gr = row0 + row; if (gr >= M) gr = M - 1;
        gload_lds16(Af + (size_t)gr * K + k0 + kg * 4, Araw[buf] + c * 16);
      }
    } else {
      #pragma unroll
      for (int j = 0; j < 2; ++j) {
        const int c = tid + 256 * j;
        const int row = c >> 2, part = c & 3;
        int gr = row0 + row; if (gr >= M) gr = M - 1;
        gload_lds16(Abf + (size_t)gr * K + k0 + part * 8, Araw[buf] + c * 16);
      }
    }
  };
  auto stageB = [&](int buf, int k0) {
    #pragma unroll
    for (int j = 0; j < 2; ++j) {
      const int c = tid + 256 * j;
      const int row = c >> 2, part = c & 3;
      gload_lds16(BT + (size_t)(col0 + row) * K + k0 + part * 8,
                  (unsigned char*)Bs[buf] + c * 16);
    }
  };

  const int nt = K >> 5;
  stageA(0, 0);
  stageB(0, 0);
  __syncthreads();

  for (int t = 0; t < nt; ++t) {
    const int cur = t & 1, nxt = cur ^ 1;
    if (t + 1 < nt) {
      stageA(nxt, (t + 1) << 5);
      stageB(nxt, (t + 1) << 5);
    }

    s16x8 af[4], bf[4];
    if constexpr (AF32) {
      const float* Ab = (const float*)Araw[cur];
      float sc[8], sh[8];
      if constexpr (AMODE == 2) {
        const int kb = (t << 5) + lq * 8;
        *(float4*)&sc[0] = *(const float4*)(abn + kb);
        *(float4*)&sc[4] = *(const float4*)(abn + kb + 4);
        *(float4*)&sh[0] = *(const float4*)(abn + K + kb);
        *(float4*)&sh[4] = *(const float4*)(abn + K + kb + 4);
      }
      #pragma unroll
      for (int f = 0; f < 4; ++f) {
        const int row = wr * 64 + f * 16 + l16;
        const int s0 = (row << 3) + ((2 * lq)     ^ (row & 7));
        const int s1 = (row << 3) + ((2 * lq + 1) ^ (row & 7));
        float4 f0 = *(const float4*)(Ab + s0 * 4);
        float4 f1 = *(const float4*)(Ab + s1 * 4);
        if constexpr (AMODE == 2) {
          f0.x = fmaxf(f0.x * sc[0] + sh[0], 0.f);
          f0.y = fmaxf(f0.y * sc[1] + sh[1], 0.f);
          f0.z = fmaxf(f0.z * sc[2] + sh[2], 0.f);
          f0.w = fmaxf(f0.w * sc[3] + sh[3], 0.f);
          f1.x = fmaxf(f1.x * sc[4] + sh[4], 0.f);
          f1.y = fmaxf(f1.y * sc[5] + sh[5], 0.f);
          f1.z = fmaxf(f1.z * sc[6] + sh[6], 0.f);
          f1.w = fmaxf(f1.w * sc[7] + sh[7], 0.f);
        }
        uint4 w;
        w.x = cvtpk(f0.x, f0.y); w.y = cvtpk(f0.z, f0.w);
        w.z = cvtpk(f1.x, f1.y); w.w = cvtpk(f1.z, f1.w);
        af[f] = *(s16x8*)&w;
      }
    } else {
      const unsigned short* Ab = (const unsigned short*)Araw[cur];
      #pragma unroll
      for (int f = 0; f < 4; ++f)
        af[f] = *(const s16x8*)&Ab[(wr * 64 + f * 16 + l16) * 32 + lq * 8];
    }
    #pragma unroll
    for (int f = 0; f < 4; ++f)
      bf[f] = *(const s16x8*)&Bs[cur][(wc * 64 + f * 16 + l16) * 32 + lq * 8];

    #pragma unroll
    for (int fm = 0; fm < 4; ++fm)
      #pragma unroll
      for (int fn = 0; fn < 4; ++fn)
        acc[fm][fn] = __builtin_amdgcn_mfma_f32_16x16x32_bf16(af[fm], bf[fn], acc[fm][fn], 0, 0, 0);

    __syncthreads();
  }

  float bv[4];
  #pragma unroll
  for (int fn = 0; fn < 4; ++fn)
    bv[fn] = bias ? bias[col0 + wc * 64 + fn * 16 + l16] : 0.f;

  float sl[4] = {0.f, 0.f, 0.f, 0.f}, ql[4] = {0.f, 0.f, 0.f, 0.f};

  #pragma unroll
  for (int fm = 0; fm < 4; ++fm) {
    #pragma unroll
    for (int r = 0; r < 4; ++r) {
      const int row = row0 + wr * 64 + fm * 16 + lq * 4 + r;
      if (row < M) {
        #pragma unroll
        for (int fn = 0; fn < 4; ++fn) {
          const int col = col0 + wc * 64 + fn * 16 + l16;
          const float v = acc[fm][fn][r] + bv[fn];
          if (BNS) { sl[fn] += v; ql[fn] += v * v; }
          if (out_bf16) ((unsigned short*)Cv)[(size_t)row * Ncols + col] = f2bf(v);
          else          ((float*)Cv)[(size_t)row * Ncols + col] = v;
        }
      }
    }
  }
  if constexpr (BNS) {
    __shared__ float csum[128], cqsum[128];
    if (tid < 128) { csum[tid] = 0.f; cqsum[tid] = 0.f; }
    __syncthreads();
    #pragma unroll
    for (int fn = 0; fn < 4; ++fn) {
      float s = sl[fn], q = ql[fn];
      s += __shfl_down(s, 16); s += __shfl_down(s, 32);
      q += __shfl_down(q, 16); q += __shfl_down(q, 32);
      if (lq == 0) {
        atomicAdd(&csum[wc * 64 + fn * 16 + l16], s);
        atomicAdd(&cqsum[wc * 64 + fn * 16 + l16], q);
      }
    }
    __syncthreads();
    if (tid < 128) {
      atomicAdd(&bnsum[col0 + tid], csum[tid]);
      atomicAdd(&bnsum[128 + col0 + tid], cqsum[tid]);
    }
  }
}

// ---------------- fused per-node GATv2 (online softmax + aggregate), bf16 I/O ----
// conv1: half-wave (32 lanes) per node, degree-sorted order; lane = 8 ch (16B).
__global__ __launch_bounds__(256) void node_conv1(
    const unsigned short* __restrict__ H1, const int* __restrict__ rowptr,
    const int* __restrict__ colv, const int* __restrict__ order,
    const float* __restrict__ att, const float* __restrict__ b1,
    unsigned short* __restrict__ out)
{
  const int tid = threadIdx.x, wave = tid >> 6, lane = tid & 63;
  const int half = lane >> 5, l32 = lane & 31;
  const int gidx = blockIdx.x * 8 + wave * 2 + half;
  if (gidx >= NN) return;
  const int node = order[gidx];
  const int ch8 = l32 * 8;
  float xr[8], at[8];
  {
    const s16x8 t = *(const s16x8*)&H1[(size_t)node * 512 + 256 + ch8];
    #pragma unroll
    for (int j = 0; j < 8; ++j) {
      xr[j] = bf2f(((const unsigned short*)&t)[j]);
      at[j] = att[ch8 + j];
    }
  }
  float m = -1e30f, s = 0.f;
  float a[8] = {0.f, 0.f, 0.f, 0.f, 0.f, 0.f, 0.f, 0.f};
  const int beg = rowptr[node], end = rowptr[node + 1];
  s16x8 xa = *(const s16x8*)&H1[(size_t)colv[beg] * 512 + ch8];
  s16x8 xb = (beg + 1 < end) ? *(const s16x8*)&H1[(size_t)colv[beg + 1] * 512 + ch8] : xa;
  for (int i = beg; i < end; ++i) {
    const int ip2 = (i + 2 < end) ? i + 2 : end - 1;
    const s16x8 xc = *(const s16x8*)&H1[(size_t)colv[ip2] * 512 + ch8];  // depth-2 prefetch
    float xv[8];
    #pragma unroll
    for (int j = 0; j < 8; ++j) xv[j] = bf2f(((const unsigned short*)&xa)[j]);
    float e = 0.f;
    #pragma unroll
    for (int j = 0; j < 8; ++j) {
      float mm = xv[j] + xr[j];
      mm = mm > 0.f ? mm : 0.2f * mm;
      e += mm * at[j];
    }
    e += __shfl_xor(e, 1); e += __shfl_xor(e, 2); e += __shfl_xor(e, 4);
    const float mn = fmaxf(m, e);
    const float scx = __expf(m - mn);
    const float w  = __expf(e - mn);
    s = s * scx + w;
    #pragma unroll
    for (int j = 0; j < 8; ++j) a[j] = a[j] * scx + w * xv[j];
    m = mn;
    xa = xb; xb = xc;
  }
  const float inv = 1.f / s;
  unsigned short ov[8];
  #pragma unroll
  for (int j = 0; j < 8; ++j) ov[j] = f2bf(fmaxf(a[j] * inv + b1[ch8 + j], 0.f));
  *(s16x8*)&out[(size_t)node * 256 + ch8] = *(const s16x8*)ov;
}

// conv2: quarter-wave (16 lanes) per node, degree-sorted order; lane = 8 ch (16B).
__global__ __launch_bounds__(256) void node_conv2(
    const unsigned short* __restrict__ H2, const int* __restrict__ rowptr,
    const int* __restrict__ colv, const int* __restrict__ order,
    const float* __restrict__ att, const float* __restrict__ b2,
    unsigned short* __restrict__ out)
{
  const int tid = threadIdx.x, wave = tid >> 6, lane = tid & 63;
  const int qr = lane >> 4, l16 = lane & 15;
  const int gidx = blockIdx.x * 16 + wave * 4 + qr;
  if (gidx >= NN) return;
  const int node = order[gidx];
  const int ch8 = l16 * 8;
  float xr[8], at[8];
  {
    const s16x8 t = *(const s16x8*)&H2[(size_t)node * 256 + 128 + ch8];
    #pragma unroll
    for (int j = 0; j < 8; ++j) {
      xr[j] = bf2f(((const unsigned short*)&t)[j]);
      at[j] = att[ch8 + j];
    }
  }
  float m = -1e30f, s = 0.f;
  float a[8] = {0.f, 0.f, 0.f, 0.f, 0.f, 0.f, 0.f, 0.f};
  const int beg = rowptr[node], end = rowptr[node + 1];
  s16x8 xa = *(const s16x8*)&H2[(size_t)colv[beg] * 256 + ch8];
  s16x8 xb = (beg + 1 < end) ? *(const s16x8*)&H2[(size_t)colv[beg + 1] * 256 + ch8] : xa;
  for (int i = beg; i < end; ++i) {
    const int ip2 = (i + 2 < end) ? i + 2 : end - 1;
    const s16x8 xc = *(const s16x8*)&H2[(size_t)colv[ip2] * 256 + ch8];
    float xv[8];
    #pragma unroll
    for (int j = 0; j < 8; ++j) xv[j] = bf2f(((const unsigned short*)&xa)[j]);
    float e = 0.f;
    #pragma unroll
    for (int j = 0; j < 8; ++j) {
      float mm = xv[j] + xr[j];
      mm = mm > 0.f ? mm : 0.2f * mm;
      e += mm * at[j];
    }
    e += __shfl_xor(e, 1); e += __shfl_xor(e, 2);
    e += __shfl_xor(e, 4); e += __shfl_xor(e, 8);
    const float mn = fmaxf(m, e);
    const float scx = __expf(m - mn);
    const float w  = __expf(e - mn);
    s = s * scx + w;
    #pragma unroll
    for (int j = 0; j < 8; ++j) a[j] = a[j] * scx + w * xv[j];
    m = mn;
    xa = xb; xb = xc;
  }
  const float inv = 1.f / s;
  unsigned short ov[8];
  #pragma unroll
  for (int j = 0; j < 8; ++j) ov[j] = f2bf(a[j] * inv + b2[ch8 + j]);
  *(s16x8*)&out[(size_t)node * 128 + ch8] = *(const s16x8*)ov;
}

// ---------------- merged weight transpose-convert (all 4 matrices, 1 launch) ----
__global__ __launch_bounds__(256) void wt_cvt_all(
    const float* __restrict__ W1l, const float* __restrict__ W1r, unsigned short* __restrict__ WT1,
    const float* __restrict__ W2l, const float* __restrict__ W2r, unsigned short* __restrict__ WT2,
    const float* __restrict__ pw1, unsigned short* __restrict__ PT1,
    const float* __restrict__ pw2, unsigned short* __restrict__ PT2)
{
  int b = blockIdx.x;
  const float *Wa, *Wb;
  unsigned short* dst;
  int K, halfN, k0, n0;
  if (b < 256)      { Wa = W1l; Wb = W1r; dst = WT1; K = 2048; halfN = 256; k0 = (b & 31) * 64; n0 = (b >> 5) * 64; }
  else if (b < 272) { b -= 256; Wa = W2l; Wb = W2r; dst = WT2; K = 256; halfN = 128; k0 = (b & 3) * 64; n0 = (b >> 2) * 64; }
  else if (b < 276) { b -= 272; Wa = pw1; Wb = pw1; dst = PT1; K = 128; halfN = 128; k0 = (b & 1) * 64; n0 = (b >> 1) * 64; }
  else              { b -= 276; Wa = pw2; Wb = pw2; dst = PT2; K = 128; halfN = 128; k0 = (b & 1) * 64; n0 = (b >> 1) * 64; }
  __shared__ float tile[64][65];
  const int tx = threadIdx.x & 63, ty = threadIdx.x >> 6;
  const float* W = (n0 < halfN) ? Wa : Wb;
  const int nb = (n0 < halfN) ? n0 : n0 - halfN;
  #pragma unroll
  for (int j = 0; j < 16; ++j) {
    const int kl = ty * 16 + j;
    tile[kl][tx] = W[(size_t)(k0 + kl) * halfN + nb + tx];
  }
  __syncthreads();
  #pragma unroll
  for (int j = 0; j < 16; ++j) {
    const int nl = ty * 16 + j;
    dst[(size_t)(n0 + nl) * K + k0 + tx] = f2bf(tile[tx][nl]);
  }
}

__global__ void bn_final(const float* __restrict__ sums, const float* __restrict__ gamma,
                         const float* __restrict__ beta, float* __restrict__ bnp, int M)
{
  const int c = threadIdx.x;
  if (c < 128) {
    const float mu  = sums[c] / (float)M;
    const float var = sums[128 + c] / (float)M - mu * mu;
    const float sc  = gamma[c] * rsqrtf(var + 1e-5f);
    bnp[c] = sc;
    bnp[128 + c] = beta[c] - mu * sc;
  }
}

// ---------------- launch ----------------
extern "C" void kernel_launch(void* const* d_in, const int* in_sizes, int n_in,
                              void* d_out, int out_size, void* d_ws, size_t ws_size,
                              hipStream_t stream)
{
  (void)in_sizes; (void)n_in; (void)out_size; (void)ws_size;
  const float* x     = (const float*)d_in[0];
  const void*  ei    = (const void*)d_in[1];
  const float* W1l   = (const float*)d_in[2];
  const float* W1r   = (const float*)d_in[3];
  const float* att1  = (const float*)d_in[4];
  const float* b1    = (const float*)d_in[5];
  const float* W2l   = (const float*)d_in[6];
  const float* W2r   = (const float*)d_in[7];
  const float* att2  = (const float*)d_in[8];
  const float* b2    = (const float*)d_in[9];
  const float* pw1   = (const float*)d_in[10];
  const float* pb1   = (const float*)d_in[11];
  const float* gamma = (const float*)d_in[12];
  const float* beta  = (const float*)d_in[13];
  const float* pw2   = (const float*)d_in[14];
  const float* pb2   = (const float*)d_in[15];

  char* ws = (char*)d_ws;
  unsigned short* H1b   = (unsigned short*)(ws + 0);           // [N][512] bf16
  unsigned short* h1b   = (unsigned short*)(ws + 51200000);    // [N][256] bf16
  unsigned short* H2b   = (unsigned short*)(ws + 76800000);    // [N][256] bf16
  unsigned short* h2b   = (unsigned short*)(ws + 102400000);   // [N][128] bf16
  float*          tbuf  = (float*)(ws + 115200000);            // [N][128] fp32
  int*            rowptr = (int*)(ws + 153600000);             // 50001*4
  int*            cnt    = (int*)(ws + 153800192);             // 50000*4
  int*            colv   = (int*)(ws + 154000384);             // 850000*4
  unsigned short* WT1    = (unsigned short*)(ws + 157400384);  // [512][2048]
  unsigned short* WT2    = (unsigned short*)(ws + 159497536);  // [256][256]
  unsigned short* PT1    = (unsigned short*)(ws + 159628608);  // [128][128]
  unsigned short* PT2    = (unsigned short*)(ws + 159661376);  // [128][128]
  float*          bnsum  = (float*)(ws + 159694144);           // 256*4
  float*          bnp    = (float*)(ws + 159695168);           // 256*4
  int*            eflag  = (int*)(ws + 159696192);             // 4
  int*            bsum   = (int*)(ws + 159696256);             // 196*4
  int*            dhist  = (int*)(ws + 159697088);             // 256*4
  int*            dcur   = (int*)(ws + 159698112);             // 256*4
  int*            order  = (int*)(ws + 159699136);             // 50000*4

  hipMemsetAsync(cnt, 0, 200000, stream);
  hipMemsetAsync(bnsum, 0, 1024, stream);

  detect_i64<<<1, 64, 0, stream>>>(ei, eflag, dhist);
  wt_cvt_all<<<280, 256, 0, stream>>>(W1l, W1r, WT1, W2l, W2r, WT2, pw1, PT1, pw2, PT2);

  const int ebl = (ETOT + 255) / 256;
  const int nsb = (NN + 255) / 256;   // 196
  csr_hist<<<ebl, 256, 0, stream>>>(ei, eflag, cnt);
  scan_blk<<<nsb, 256, 0, stream>>>(cnt, rowptr + 1, bsum, dhist);
  scan_tops<<<1, 256, 0, stream>>>(bsum, nsb, dhist, dcur);
  scan_add<<<nsb, 256, 0, stream>>>(bsum, rowptr, cnt, dcur, order);
  // scatter cursor = copy of rowptr (first NN entries); pos indexes colv directly
  hipMemcpyAsync(cnt, rowptr, 200000, hipMemcpyDeviceToDevice, stream);
  csr_scatter<<<ebl, 256, 0, stream>>>(ei, eflag, cnt, colv);

  const int nb256 = (NN + 255) / 256;   // 196 row blocks for gemm8
  const int nby   = (NN + 127) / 128;   // 391 row blocks for gemm_t

  // conv1: H1 = x @ [W1l|W1r]  (fp32 A, 256x128 8-wave tile; R12-proven best)
  gemm8<true><<<nb256 * 4, 512, 0, stream>>>(x, WT1, H1b, nullptr, NN, 2048, 512, 1, 4, nb256 * 4);
  node_conv1<<<(NN + 7) / 8, 256, 0, stream>>>(H1b, rowptr, colv, order, att1, b1, h1b);

  // conv2: H2 = h1 @ [W2l|W2r]  (bf16 A, 256x128 8-wave tile)
  gemm8<false><<<nb256 * 2, 512, 0, stream>>>(h1b, WT2, H2b, nullptr, NN, 256, 256, 1, 2, nb256 * 2);
  node_conv2<<<(NN + 15) / 16, 256, 0, stream>>>(H2b, rowptr, colv, order, att2, b2, h2b);

  // projection head: proj1 (+fused BN stats, register-first) -> bn_final -> proj2
  gemm_t<0, true><<<nby, 256, 0, stream>>>(h2b, PT1, tbuf, pb1, nullptr, bnsum, NN, 128, 128, 0, 1, nby);
  bn_final<<<1, 128, 0, stream>>>(bnsum, gamma, beta, bnp, NN);
  gemm_t<2, false><<<nby, 256, 0, stream>>>(tbuf, PT2, (float*)d_out, pb2, bnp, nullptr, NN, 128, 128, 0, 1, nby);
}

// Round 18
// 523.907 us; speedup vs baseline: 1.4383x; 1.4383x over previous
//
#include <hip/hip_runtime.h>
#include <hip/hip_bf16.h>
#include <cstdint>
#include <cstddef>

#define NN 50000
#define NE 800000
#define ETOT (NN + NE)   // 850000 edges incl. self loops

typedef float f32x4 __attribute__((ext_vector_type(4)));
typedef short s16x8 __attribute__((ext_vector_type(8)));

__device__ __forceinline__ unsigned short f2bf(float f) {
  unsigned u = __float_as_uint(f);
  u += 0x7FFFu + ((u >> 16) & 1u);   // RNE
  return (unsigned short)(u >> 16);
}
__device__ __forceinline__ float bf2f(unsigned short u) {
  return __uint_as_float(((unsigned)u) << 16);
}
__device__ __forceinline__ unsigned cvtpk(float lo, float hi) {  // 2xf32 -> packed bf16 (RNE)
  unsigned r;
  asm("v_cvt_pk_bf16_f32 %0, %1, %2" : "=v"(r) : "v"(lo), "v"(hi));
  return r;
}
typedef const __attribute__((address_space(1))) void* gas_t;
typedef __attribute__((address_space(3))) void* las_t;
__device__ __forceinline__ void gload_lds16(const void* g, void* l) {
  __builtin_amdgcn_global_load_lds((gas_t)g, (las_t)l, 16, 0, 0);
}

// edge_index may arrive as int32 or int64; detect on device (deterministic input).
__global__ void detect_i64(const void* __restrict__ ei, int* __restrict__ flag) {
  const long long v = ((const long long*)ei)[threadIdx.x];
  const bool ok = (v >= 0 && v < NN);
  const unsigned long long m = __ballot(ok);
  if (threadIdx.x == 0) *flag = (m == ~0ULL) ? 1 : 0;
}
__device__ __forceinline__ void load_edge(const void* __restrict__ ei, int is64,
                                          int eidx, int& src, int& dst) {
  if (eidx >= NE) { src = dst = eidx - NE; return; }
  if (is64) {
    src = (int)((const long long*)ei)[eidx];
    dst = (int)((const long long*)ei)[NE + eidx];
  } else {
    src = ((const int*)ei)[eidx];
    dst = ((const int*)ei)[NE + eidx];
  }
}

// ---------------- CSR build (by dst) ----------------
__global__ __launch_bounds__(256) void csr_hist(
    const void* __restrict__ ei, const int* __restrict__ flag, int* __restrict__ cnt)
{
  const int e = blockIdx.x * 256 + threadIdx.x;
  if (e >= ETOT) return;
  int src, dst;
  load_edge(ei, *flag, e, src, dst);
  atomicAdd(&cnt[dst], 1);
}

__global__ __launch_bounds__(256) void scan_blk(
    const int* __restrict__ cnt, int* __restrict__ rp1, int* __restrict__ bsum)
{
  const int tid = threadIdx.x, lane = tid & 63, w = tid >> 6;
  const int i = blockIdx.x * 256 + tid;
  int s = (i < NN) ? cnt[i] : 0;
  #pragma unroll
  for (int off = 1; off < 64; off <<= 1) {
    int t = __shfl_up(s, off);
    if (lane >= off) s += t;
  }
  __shared__ int wsum[4];
  if (lane == 63) wsum[w] = s;
  __syncthreads();
  int add = 0;
  #pragma unroll
  for (int k = 0; k < 4; ++k) if (k < w) add += wsum[k];
  s += add;
  if (i < NN) rp1[i] = s;
  if (tid == 255) bsum[blockIdx.x] = s;
}

__global__ __launch_bounds__(256) void scan_tops(int* __restrict__ bsum, int nb)
{
  const int tid = threadIdx.x, lane = tid & 63, w = tid >> 6;
  int s = (tid < nb) ? bsum[tid] : 0;
  #pragma unroll
  for (int off = 1; off < 64; off <<= 1) {
    int t = __shfl_up(s, off);
    if (lane >= off) s += t;
  }
  __shared__ int wsum[4];
  if (lane == 63) wsum[w] = s;
  __syncthreads();
  int add = 0;
  #pragma unroll
  for (int k = 0; k < 4; ++k) if (k < w) add += wsum[k];
  s += add;
  if (tid < nb) bsum[tid] = s;   // inclusive block sums
}

__global__ __launch_bounds__(256) void scan_add(
    const int* __restrict__ bsum, int* __restrict__ rowptr)
{
  const int i = blockIdx.x * 256 + threadIdx.x;
  if (i == 0) rowptr[0] = 0;
  if (i < NN) rowptr[i + 1] += (blockIdx.x > 0) ? bsum[blockIdx.x - 1] : 0;
}

// cur[] preloaded with rowptr[] (d2d copy); pos = cur[dst]++ directly indexes colv
__global__ __launch_bounds__(256) void csr_scatter(
    const void* __restrict__ ei, const int* __restrict__ flag,
    int* __restrict__ cur, int* __restrict__ colv)
{
  const int e = blockIdx.x * 256 + threadIdx.x;
  if (e >= ETOT) return;
  int src, dst;
  load_edge(ei, *flag, e, src, dst);
  const int pos = atomicAdd(&cur[dst], 1);
  colv[pos] = src;
}

// ---------------- gemm8: 256x128 tile, 8 waves, BK=32, double-buffered ----------
// C[M][Nc] = A[M][K] @ BT[Nc][K]^T (+bias). One __syncthreads per K-step,
// 1-deep async prefetch via global_load_lds.
// AF32: A fp32 raw in LDS [row][8 slots] kg-XOR (coalesced src), cvt at read.
template<bool AF32>
__global__ __launch_bounds__(512) void gemm8(
    const void* __restrict__ Av, const unsigned short* __restrict__ BT,
    void* __restrict__ Cv, const float* __restrict__ bias,
    int M, int K, int Ncols, int out_bf16, int nbx, int nwg)
{
  constexpr int ABYTES = AF32 ? 256 * 32 * 4 : 256 * 32 * 2;
  __shared__ __align__(16) unsigned char Araw[2][ABYTES];
  __shared__ __align__(16) unsigned short Bs[2][128 * 32];

  int bid = blockIdx.x;
  {  // bijective XCD-chunked swizzle (m204)
    const int q = nwg >> 3, r = nwg & 7;
    const int xcd = bid & 7, idx = bid >> 3;
    bid = (xcd < r ? xcd * (q + 1) : r * (q + 1) + (xcd - r) * q) + idx;
  }
  const int bx = bid % nbx, by = bid / nbx;
  const int row0 = by * 256, col0 = bx * 128;
  const int tid = threadIdx.x, wave = tid >> 6, lane = tid & 63;
  const int l16 = lane & 15, lq = lane >> 4;
  const int wr = wave >> 1, wc = wave & 1;   // wr 0..3 (64-row bands), wc 0..1

  const unsigned short* Abf = (const unsigned short*)Av;
  const float*          Af  = (const float*)Av;

  f32x4 acc[4][4];
  #pragma unroll
  for (int i = 0; i < 4; ++i)
    #pragma unroll
    for (int j = 0; j < 4; ++j)
      #pragma unroll
      for (int r = 0; r < 4; ++r) acc[i][j][r] = 0.f;

  auto stageA = [&](int buf, int k0) {
    if constexpr (AF32) {
      // 2048 chunks: row = c>>3 in [0,256), slot = c&7, src kg = slot^(row&7)
      #pragma unroll
      for (int j = 0; j < 4; ++j) {
        const int c = tid + 512 * j;
        const int row = c >> 3;
        const int kg = (c & 7) ^ (row & 7);
        int gr = row0 + row; if (gr >= M) gr = M - 1;
        gload_lds16(Af + (size_t)gr * K + k0 + kg * 4, Araw[buf] + c * 16);
      }
    } else {
      // 1024 chunks: row = c>>2 in [0,256), part = c&3
      #pragma unroll
      for (int j = 0; j < 2; ++j) {
        const int c = tid + 512 * j;
        const int row = c >> 2, part = c & 3;
        int gr = row0 + row; if (gr >= M) gr = M - 1;
        gload_lds16(Abf + (size_t)gr * K + k0 + part * 8, Araw[buf] + c * 16);
      }
    }
  };
  auto stageB = [&](int buf, int k0) {
    const int c = tid;
    const int row = c >> 2, part = c & 3;
    gload_lds16(BT + (size_t)(col0 + row) * K + k0 + part * 8,
                (unsigned char*)Bs[buf] + c * 16);
  };

  const int nt = K >> 5;
  stageA(0, 0);
  stageB(0, 0);
  __syncthreads();

  for (int t = 0; t < nt; ++t) {
    const int cur = t & 1, nxt = cur ^ 1;
    if (t + 1 < nt) {   // async prefetch of next tile, in flight across MFMAs
      stageA(nxt, (t + 1) << 5);
      stageB(nxt, (t + 1) << 5);
    }

    s16x8 af[4], bf[4];
    if constexpr (AF32) {
      const float* Ab = (const float*)Araw[cur];
      #pragma unroll
      for (int f = 0; f < 4; ++f) {
        const int row = wr * 64 + f * 16 + l16;
        const int s0 = (row << 3) + ((2 * lq)     ^ (row & 7));
        const int s1 = (row << 3) + ((2 * lq + 1) ^ (row & 7));
        const float4 f0 = *(const float4*)(Ab + s0 * 4);
        const float4 f1 = *(const float4*)(Ab + s1 * 4);
        uint4 w;
        w.x = cvtpk(f0.x, f0.y); w.y = cvtpk(f0.z, f0.w);
        w.z = cvtpk(f1.x, f1.y); w.w = cvtpk(f1.z, f1.w);
        af[f] = *(s16x8*)&w;
      }
    } else {
      const unsigned short* Ab = (const unsigned short*)Araw[cur];
      #pragma unroll
      for (int f = 0; f < 4; ++f)
        af[f] = *(const s16x8*)&Ab[(wr * 64 + f * 16 + l16) * 32 + lq * 8];
    }
    #pragma unroll
    for (int f = 0; f < 4; ++f)
      bf[f] = *(const s16x8*)&Bs[cur][(wc * 64 + f * 16 + l16) * 32 + lq * 8];

    #pragma unroll
    for (int fm = 0; fm < 4; ++fm)
      #pragma unroll
      for (int fn = 0; fn < 4; ++fn)
        acc[fm][fn] = __builtin_amdgcn_mfma_f32_16x16x32_bf16(af[fm], bf[fn], acc[fm][fn], 0, 0, 0);

    __syncthreads();
  }

  float bv[4];
  #pragma unroll
  for (int fn = 0; fn < 4; ++fn)
    bv[fn] = bias ? bias[col0 + wc * 64 + fn * 16 + l16] : 0.f;

  // C/D layout: col = l16, row = lq*4 + r (verified m89/m91 + rounds 2-16)
  #pragma unroll
  for (int fm = 0; fm < 4; ++fm) {
    #pragma unroll
    for (int r = 0; r < 4; ++r) {
      const int row = row0 + wr * 64 + fm * 16 + lq * 4 + r;
      if (row < M) {
        #pragma unroll
        for (int fn = 0; fn < 4; ++fn) {
          const int col = col0 + wc * 64 + fn * 16 + l16;
          const float v = acc[fm][fn][r] + bv[fn];
          if (out_bf16) ((unsigned short*)Cv)[(size_t)row * Ncols + col] = f2bf(v);
          else          ((float*)Cv)[(size_t)row * Ncols + col] = v;
        }
      }
    }
  }
}

// ---------------- gemm_t: 128x128 tile, 4 waves (R8 structure) — small GEMMs ----
// AMODE: 0 = A bf16; 2 = A fp32 + fused BN affine+ReLU at frag read.
// BNS: fused BN stats, register-first (R15-proven).
template<int AMODE, bool BNS>
__global__ __launch_bounds__(256) void gemm_t(
    const void* __restrict__ Av, const unsigned short* __restrict__ BT,
    void* __restrict__ Cv, const float* __restrict__ bias,
    const float* __restrict__ abn, float* __restrict__ bnsum,
    int M, int K, int Ncols, int out_bf16, int nbx, int nwg)
{
  constexpr bool AF32 = (AMODE > 0);
  __shared__ __align__(16) unsigned char Araw[2][AF32 ? 128 * 32 * 4 : 128 * 32 * 2];
  __shared__ __align__(16) unsigned short Bs[2][128 * 32];

  int bid = blockIdx.x;
  {
    const int q = nwg >> 3, r = nwg & 7;
    const int xcd = bid & 7, idx = bid >> 3;
    bid = (xcd < r ? xcd * (q + 1) : r * (q + 1) + (xcd - r) * q) + idx;
  }
  const int bx = bid % nbx, by = bid / nbx;
  const int row0 = by * 128, col0 = bx * 128;
  const int tid = threadIdx.x, wave = tid >> 6, lane = tid & 63;
  const int l16 = lane & 15, lq = lane >> 4;
  const int wr = wave >> 1, wc = wave & 1;

  const unsigned short* Abf = (const unsigned short*)Av;
  const float*          Af  = (const float*)Av;

  f32x4 acc[4][4];
  #pragma unroll
  for (int i = 0; i < 4; ++i)
    #pragma unroll
    for (int j = 0; j < 4; ++j)
      #pragma unroll
      for (int r = 0; r < 4; ++r) acc[i][j][r] = 0.f;

  auto stageA = [&](int buf, int k0) {
    if constexpr (AF32) {
      #pragma unroll
      for (int j = 0; j < 4; ++j) {
        const int c = tid + 256 * j;
        const int row = c >> 3;
        const int kg = (c & 7) ^ (row & 7);
        int gr = row0 + row; if (gr >= M) gr = M - 1;
        gload_lds16(Af + (size_t)gr * K + k0 + kg * 4, Araw[buf] + c * 16);
      }
    } else {
      #pragma unroll
      for (int j = 0; j < 2; ++j) {
        const int c = tid + 256 * j;
        const int row = c >> 2, part = c & 3;
        int gr = row0 + row; if (gr >= M) gr = M - 1;
        gload_lds16(Abf + (size_t)gr * K + k0 + part * 8, Araw[buf] + c * 16);
      }
    }
  };
  auto stageB = [&](int buf, int k0) {
    #pragma unroll
    for (int j = 0; j < 2; ++j) {
      const int c = tid + 256 * j;
      const int row = c >> 2, part = c & 3;
      gload_lds16(BT + (size_t)(col0 + row) * K + k0 + part * 8,
                  (unsigned char*)Bs[buf] + c * 16);
    }
  };

  const int nt = K >> 5;
  stageA(0, 0);
  stageB(0, 0);
  __syncthreads();

  for (int t = 0; t < nt; ++t) {
    const int cur = t & 1, nxt = cur ^ 1;
    if (t + 1 < nt) {
      stageA(nxt, (t + 1) << 5);
      stageB(nxt, (t + 1) << 5);
    }

    s16x8 af[4], bf[4];
    if constexpr (AF32) {
      const float* Ab = (const float*)Araw[cur];
      float sc[8], sh[8];
      if constexpr (AMODE == 2) {
        const int kb = (t << 5) + lq * 8;
        *(float4*)&sc[0] = *(const float4*)(abn + kb);
        *(float4*)&sc[4] = *(const float4*)(abn + kb + 4);
        *(float4*)&sh[0] = *(const float4*)(abn + K + kb);
        *(float4*)&sh[4] = *(const float4*)(abn + K + kb + 4);
      }
      #pragma unroll
      for (int f = 0; f < 4; ++f) {
        const int row = wr * 64 + f * 16 + l16;
        const int s0 = (row << 3) + ((2 * lq)     ^ (row & 7));
        const int s1 = (row << 3) + ((2 * lq + 1) ^ (row & 7));
        float4 f0 = *(const float4*)(Ab + s0 * 4);
        float4 f1 = *(const float4*)(Ab + s1 * 4);
        if constexpr (AMODE == 2) {
          f0.x = fmaxf(f0.x * sc[0] + sh[0], 0.f);
          f0.y = fmaxf(f0.y * sc[1] + sh[1], 0.f);
          f0.z = fmaxf(f0.z * sc[2] + sh[2], 0.f);
          f0.w = fmaxf(f0.w * sc[3] + sh[3], 0.f);
          f1.x = fmaxf(f1.x * sc[4] + sh[4], 0.f);
          f1.y = fmaxf(f1.y * sc[5] + sh[5], 0.f);
          f1.z = fmaxf(f1.z * sc[6] + sh[6], 0.f);
          f1.w = fmaxf(f1.w * sc[7] + sh[7], 0.f);
        }
        uint4 w;
        w.x = cvtpk(f0.x, f0.y); w.y = cvtpk(f0.z, f0.w);
        w.z = cvtpk(f1.x, f1.y); w.w = cvtpk(f1.z, f1.w);
        af[f] = *(s16x8*)&w;
      }
    } else {
      const unsigned short* Ab = (const unsigned short*)Araw[cur];
      #pragma unroll
      for (int f = 0; f < 4; ++f)
        af[f] = *(const s16x8*)&Ab[(wr * 64 + f * 16 + l16) * 32 + lq * 8];
    }
    #pragma unroll
    for (int f = 0; f < 4; ++f)
      bf[f] = *(const s16x8*)&Bs[cur][(wc * 64 + f * 16 + l16) * 32 + lq * 8];

    #pragma unroll
    for (int fm = 0; fm < 4; ++fm)
      #pragma unroll
      for (int fn = 0; fn < 4; ++fn)
        acc[fm][fn] = __builtin_amdgcn_mfma_f32_16x16x32_bf16(af[fm], bf[fn], acc[fm][fn], 0, 0, 0);

    __syncthreads();
  }

  float bv[4];
  #pragma unroll
  for (int fn = 0; fn < 4; ++fn)
    bv[fn] = bias ? bias[col0 + wc * 64 + fn * 16 + l16] : 0.f;

  float sl[4] = {0.f, 0.f, 0.f, 0.f}, ql[4] = {0.f, 0.f, 0.f, 0.f};

  #pragma unroll
  for (int fm = 0; fm < 4; ++fm) {
    #pragma unroll
    for (int r = 0; r < 4; ++r) {
      const int row = row0 + wr * 64 + fm * 16 + lq * 4 + r;
      if (row < M) {
        #pragma unroll
        for (int fn = 0; fn < 4; ++fn) {
          const int col = col0 + wc * 64 + fn * 16 + l16;
          const float v = acc[fm][fn][r] + bv[fn];
          if (BNS) { sl[fn] += v; ql[fn] += v * v; }
          if (out_bf16) ((unsigned short*)Cv)[(size_t)row * Ncols + col] = f2bf(v);
          else          ((float*)Cv)[(size_t)row * Ncols + col] = v;
        }
      }
    }
  }
  if constexpr (BNS) {
    __shared__ float csum[128], cqsum[128];
    if (tid < 128) { csum[tid] = 0.f; cqsum[tid] = 0.f; }
    __syncthreads();
    #pragma unroll
    for (int fn = 0; fn < 4; ++fn) {
      float s = sl[fn], q = ql[fn];
      s += __shfl_down(s, 16); s += __shfl_down(s, 32);   // reduce across lq
      q += __shfl_down(q, 16); q += __shfl_down(q, 32);
      if (lq == 0) {
        atomicAdd(&csum[wc * 64 + fn * 16 + l16], s);
        atomicAdd(&cqsum[wc * 64 + fn * 16 + l16], q);
      }
    }
    __syncthreads();
    if (tid < 128) {
      atomicAdd(&bnsum[col0 + tid], csum[tid]);
      atomicAdd(&bnsum[128 + col0 + tid], cqsum[tid]);
    }
  }
}

// ---------------- fused per-node GATv2 (online softmax + aggregate), bf16 I/O ----
// conv1: half-wave (32 lanes) per node; lane covers 8 ch (16B loads).
// Head = 8-lane group (8 lanes x 8 ch = 64 ch); reduce = shfl_xor 1,2,4.
__global__ __launch_bounds__(256) void node_conv1(
    const unsigned short* __restrict__ H1, const int* __restrict__ rowptr,
    const int* __restrict__ colv, const float* __restrict__ att,
    const float* __restrict__ b1, unsigned short* __restrict__ out)
{
  const int tid = threadIdx.x, wave = tid >> 6, lane = tid & 63;
  const int half = lane >> 5, l32 = lane & 31;
  const int node = blockIdx.x * 8 + wave * 2 + half;
  if (node >= NN) return;
  const int ch8 = l32 * 8;
  float xr[8], at[8];
  {
    const s16x8 t = *(const s16x8*)&H1[(size_t)node * 512 + 256 + ch8];
    #pragma unroll
    for (int j = 0; j < 8; ++j) {
      xr[j] = bf2f(((const unsigned short*)&t)[j]);
      at[j] = att[ch8 + j];
    }
  }
  float m = -1e30f, s = 0.f;
  float a[8] = {0.f, 0.f, 0.f, 0.f, 0.f, 0.f, 0.f, 0.f};
  const int beg = rowptr[node], end = rowptr[node + 1];
  s16x8 xa = *(const s16x8*)&H1[(size_t)colv[beg] * 512 + ch8];
  s16x8 xb = (beg + 1 < end) ? *(const s16x8*)&H1[(size_t)colv[beg + 1] * 512 + ch8] : xa;
  for (int i = beg; i < end; ++i) {
    const int ip2 = (i + 2 < end) ? i + 2 : end - 1;
    const s16x8 xc = *(const s16x8*)&H1[(size_t)colv[ip2] * 512 + ch8];  // depth-2 prefetch
    float xv[8];
    #pragma unroll
    for (int j = 0; j < 8; ++j) xv[j] = bf2f(((const unsigned short*)&xa)[j]);
    float e = 0.f;
    #pragma unroll
    for (int j = 0; j < 8; ++j) {
      float mm = xv[j] + xr[j];
      mm = mm > 0.f ? mm : 0.2f * mm;
      e += mm * at[j];
    }
    e += __shfl_xor(e, 1); e += __shfl_xor(e, 2); e += __shfl_xor(e, 4);
    const float mn = fmaxf(m, e);
    const float scx = __expf(m - mn);
    const float w  = __expf(e - mn);
    s = s * scx + w;
    #pragma unroll
    for (int j = 0; j < 8; ++j) a[j] = a[j] * scx + w * xv[j];
    m = mn;
    xa = xb; xb = xc;
  }
  const float inv = 1.f / s;
  unsigned short ov[8];
  #pragma unroll
  for (int j = 0; j < 8; ++j) ov[j] = f2bf(fmaxf(a[j] * inv + b1[ch8 + j], 0.f));
  *(s16x8*)&out[(size_t)node * 256 + ch8] = *(const s16x8*)ov;
}

// conv2: quarter-wave (16 lanes) per node; lane covers 8 ch (16B loads).
// Single head of 128 ch; reduce = shfl_xor 1,2,4,8.
__global__ __launch_bounds__(256) void node_conv2(
    const unsigned short* __restrict__ H2, const int* __restrict__ rowptr,
    const int* __restrict__ colv, const float* __restrict__ att,
    const float* __restrict__ b2, unsigned short* __restrict__ out)
{
  const int tid = threadIdx.x, wave = tid >> 6, lane = tid & 63;
  const int qr = lane >> 4, l16 = lane & 15;
  const int node = blockIdx.x * 16 + wave * 4 + qr;
  if (node >= NN) return;
  const int ch8 = l16 * 8;
  float xr[8], at[8];
  {
    const s16x8 t = *(const s16x8*)&H2[(size_t)node * 256 + 128 + ch8];
    #pragma unroll
    for (int j = 0; j < 8; ++j) {
      xr[j] = bf2f(((const unsigned short*)&t)[j]);
      at[j] = att[ch8 + j];
    }
  }
  float m = -1e30f, s = 0.f;
  float a[8] = {0.f, 0.f, 0.f, 0.f, 0.f, 0.f, 0.f, 0.f};
  const int beg = rowptr[node], end = rowptr[node + 1];
  s16x8 xa = *(const s16x8*)&H2[(size_t)colv[beg] * 256 + ch8];
  s16x8 xb = (beg + 1 < end) ? *(const s16x8*)&H2[(size_t)colv[beg + 1] * 256 + ch8] : xa;
  for (int i = beg; i < end; ++i) {
    const int ip2 = (i + 2 < end) ? i + 2 : end - 1;
    const s16x8 xc = *(const s16x8*)&H2[(size_t)colv[ip2] * 256 + ch8];
    float xv[8];
    #pragma unroll
    for (int j = 0; j < 8; ++j) xv[j] = bf2f(((const unsigned short*)&xa)[j]);
    float e = 0.f;
    #pragma unroll
    for (int j = 0; j < 8; ++j) {
      float mm = xv[j] + xr[j];
      mm = mm > 0.f ? mm : 0.2f * mm;
      e += mm * at[j];
    }
    e += __shfl_xor(e, 1); e += __shfl_xor(e, 2);
    e += __shfl_xor(e, 4); e += __shfl_xor(e, 8);
    const float mn = fmaxf(m, e);
    const float scx = __expf(m - mn);
    const float w  = __expf(e - mn);
    s = s * scx + w;
    #pragma unroll
    for (int j = 0; j < 8; ++j) a[j] = a[j] * scx + w * xv[j];
    m = mn;
    xa = xb; xb = xc;
  }
  const float inv = 1.f / s;
  unsigned short ov[8];
  #pragma unroll
  for (int j = 0; j < 8; ++j) ov[j] = f2bf(a[j] * inv + b2[ch8 + j]);
  *(s16x8*)&out[(size_t)node * 128 + ch8] = *(const s16x8*)ov;
}

// ---------------- merged weight transpose-convert (all 4 matrices, 1 launch) ----
// 64x64 tiles. blocks: [0,256) WT1, [256,272) WT2, [272,276) PT1, [276,280) PT2.
__global__ __launch_bounds__(256) void wt_cvt_all(
    const float* __restrict__ W1l, const float* __restrict__ W1r, unsigned short* __restrict__ WT1,
    const float* __restrict__ W2l, const float* __restrict__ W2r, unsigned short* __restrict__ WT2,
    const float* __restrict__ pw1, unsigned short* __restrict__ PT1,
    const float* __restrict__ pw2, unsigned short* __restrict__ PT2)
{
  int b = blockIdx.x;
  const float *Wa, *Wb;
  unsigned short* dst;
  int K, halfN, k0, n0;
  if (b < 256)      { Wa = W1l; Wb = W1r; dst = WT1; K = 2048; halfN = 256; k0 = (b & 31) * 64; n0 = (b >> 5) * 64; }
  else if (b < 272) { b -= 256; Wa = W2l; Wb = W2r; dst = WT2; K = 256; halfN = 128; k0 = (b & 3) * 64; n0 = (b >> 2) * 64; }
  else if (b < 276) { b -= 272; Wa = pw1; Wb = pw1; dst = PT1; K = 128; halfN = 128; k0 = (b & 1) * 64; n0 = (b >> 1) * 64; }
  else              { b -= 276; Wa = pw2; Wb = pw2; dst = PT2; K = 128; halfN = 128; k0 = (b & 1) * 64; n0 = (b >> 1) * 64; }
  __shared__ float tile[64][65];
  const int tx = threadIdx.x & 63, ty = threadIdx.x >> 6;
  const float* W = (n0 < halfN) ? Wa : Wb;
  const int nb = (n0 < halfN) ? n0 : n0 - halfN;
  #pragma unroll
  for (int j = 0; j < 16; ++j) {
    const int kl = ty * 16 + j;
    tile[kl][tx] = W[(size_t)(k0 + kl) * halfN + nb + tx];
  }
  __syncthreads();
  #pragma unroll
  for (int j = 0; j < 16; ++j) {
    const int nl = ty * 16 + j;
    dst[(size_t)(n0 + nl) * K + k0 + tx] = f2bf(tile[tx][nl]);
  }
}

__global__ void bn_final(const float* __restrict__ sums, const float* __restrict__ gamma,
                         const float* __restrict__ beta, float* __restrict__ bnp, int M)
{
  const int c = threadIdx.x;
  if (c < 128) {
    const float mu  = sums[c] / (float)M;
    const float var = sums[128 + c] / (float)M - mu * mu;
    const float sc  = gamma[c] * rsqrtf(var + 1e-5f);
    bnp[c] = sc;
    bnp[128 + c] = beta[c] - mu * sc;
  }
}

// ---------------- launch ----------------
extern "C" void kernel_launch(void* const* d_in, const int* in_sizes, int n_in,
                              void* d_out, int out_size, void* d_ws, size_t ws_size,
                              hipStream_t stream)
{
  (void)in_sizes; (void)n_in; (void)out_size; (void)ws_size;
  const float* x     = (const float*)d_in[0];
  const void*  ei    = (const void*)d_in[1];
  const float* W1l   = (const float*)d_in[2];
  const float* W1r   = (const float*)d_in[3];
  const float* att1  = (const float*)d_in[4];
  const float* b1    = (const float*)d_in[5];
  const float* W2l   = (const float*)d_in[6];
  const float* W2r   = (const float*)d_in[7];
  const float* att2  = (const float*)d_in[8];
  const float* b2    = (const float*)d_in[9];
  const float* pw1   = (const float*)d_in[10];
  const float* pb1   = (const float*)d_in[11];
  const float* gamma = (const float*)d_in[12];
  const float* beta  = (const float*)d_in[13];
  const float* pw2   = (const float*)d_in[14];
  const float* pb2   = (const float*)d_in[15];

  char* ws = (char*)d_ws;
  unsigned short* H1b   = (unsigned short*)(ws + 0);           // [N][512] bf16
  unsigned short* h1b   = (unsigned short*)(ws + 51200000);    // [N][256] bf16
  unsigned short* H2b   = (unsigned short*)(ws + 76800000);    // [N][256] bf16
  unsigned short* h2b   = (unsigned short*)(ws + 102400000);   // [N][128] bf16
  float*          tbuf  = (float*)(ws + 115200000);            // [N][128] fp32
  int*            rowptr = (int*)(ws + 153600000);             // 50001*4
  int*            cnt    = (int*)(ws + 153800192);             // 50000*4
  int*            colv   = (int*)(ws + 154000384);             // 850000*4
  unsigned short* WT1    = (unsigned short*)(ws + 157400384);  // [512][2048]
  unsigned short* WT2    = (unsigned short*)(ws + 159497536);  // [256][256]
  unsigned short* PT1    = (unsigned short*)(ws + 159628608);  // [128][128]
  unsigned short* PT2    = (unsigned short*)(ws + 159661376);  // [128][128]
  float*          bnsum  = (float*)(ws + 159694144);
  float*          bnp    = (float*)(ws + 159695168);
  int*            eflag  = (int*)(ws + 159696192);
  int*            bsum   = (int*)(ws + 159696256);             // 196*4

  hipMemsetAsync(cnt, 0, 200000, stream);
  hipMemsetAsync(bnsum, 0, 1024, stream);

  detect_i64<<<1, 64, 0, stream>>>(ei, eflag);
  wt_cvt_all<<<280, 256, 0, stream>>>(W1l, W1r, WT1, W2l, W2r, WT2, pw1, PT1, pw2, PT2);

  const int ebl = (ETOT + 255) / 256;
  const int nsb = (NN + 255) / 256;   // 196
  csr_hist<<<ebl, 256, 0, stream>>>(ei, eflag, cnt);
  scan_blk<<<nsb, 256, 0, stream>>>(cnt, rowptr + 1, bsum);
  scan_tops<<<1, 256, 0, stream>>>(bsum, nsb);
  scan_add<<<nsb, 256, 0, stream>>>(bsum, rowptr);
  // scatter cursor = copy of rowptr (first NN entries); pos indexes colv directly
  hipMemcpyAsync(cnt, rowptr, 200000, hipMemcpyDeviceToDevice, stream);
  csr_scatter<<<ebl, 256, 0, stream>>>(ei, eflag, cnt, colv);

  const int nb256 = (NN + 255) / 256;   // 196 row blocks for gemm8
  const int nby   = (NN + 127) / 128;   // 391 row blocks for gemm_t

  // conv1: H1 = x @ [W1l|W1r]  (fp32 A, 256x128 8-wave tile; R12-proven best)
  gemm8<true><<<nb256 * 4, 512, 0, stream>>>(x, WT1, H1b, nullptr, NN, 2048, 512, 1, 4, nb256 * 4);
  node_conv1<<<(NN + 7) / 8, 256, 0, stream>>>(H1b, rowptr, colv, att1, b1, h1b);

  // conv2: H2 = h1 @ [W2l|W2r]  (bf16 A, 256x128 8-wave tile)
  gemm8<false><<<nb256 * 2, 512, 0, stream>>>(h1b, WT2, H2b, nullptr, NN, 256, 256, 1, 2, nb256 * 2);
  node_conv2<<<(NN + 15) / 16, 256, 0, stream>>>(H2b, rowptr, colv, att2, b2, h2b);

  // projection head: proj1 (+fused BN stats, register-first) -> bn_final -> proj2
  gemm_t<0, true><<<nby, 256, 0, stream>>>(h2b, PT1, tbuf, pb1, nullptr, bnsum, NN, 128, 128, 0, 1, nby);
  bn_final<<<1, 128, 0, stream>>>(bnsum, gamma, beta, bnp, NN);
  gemm_t<2, false><<<nby, 256, 0, stream>>>(tbuf, PT2, (float*)d_out, pb2, bnp, nullptr, NN, 128, 128, 0, 1, nby);
}